// Round 2
// baseline (583.601 us; speedup 1.0000x reference)
//
#include <hip/hip_runtime.h>
#include <stdint.h>

#define T_LEN 2048
#define BATCH 64
#define I_DIM 256
#define H_DIM 256
#define N3    768                  // 3*H
#define M_ROWS (T_LEN*BATCH)       // 131072
#define L2E 1.4426950408889634f

typedef _Float16 f16;
typedef __attribute__((ext_vector_type(4))) float  f32x4;
typedef __attribute__((ext_vector_type(4))) unsigned int   u32x4;
typedef __attribute__((ext_vector_type(8))) _Float16 f16x8;
typedef __attribute__((ext_vector_type(4))) _Float16 f16x4;

// ---------------------------------------------------------------------------
// Kernel 0: convert W_ih [768,256] f32 -> f16, gate scaling baked in
// (-log2e for r,z rows; -2*log2e for n rows).
// ---------------------------------------------------------------------------
__global__ void convert_w(const float* __restrict__ W,
                          f16* __restrict__ Whf) {
    int idx = blockIdx.x * 256 + threadIdx.x;       // 768*256 total
    int row = idx >> 8;
    float scale = (row < 2*H_DIM) ? -L2E : -2.0f*L2E;
    Whf[idx] = (f16)(W[idx] * scale);
}

// ---------------------------------------------------------------------------
// Kernel 1: gx[M,768](f16) = X[M,256](f32->f16) * W^T(f16), single-pass f16
// MFMA. BM=BN=128, BK=64, 256 threads (2x2 waves), XOR-swizzled LDS, 32 KiB.
// ---------------------------------------------------------------------------
#define BM 128
#define BN 128
#define BK 64

__device__ __forceinline__ int lds_swz(int row, int kbyte) {
    // row stride 128B (64 f16); XOR 16B-unit index with row&7 -> conflict-free b128 reads
    return row * 128 + (kbyte ^ ((row & 7) << 4));
}

__global__ __launch_bounds__(256, 4) void gemm_gx(
        const float* __restrict__ X,
        const f16* __restrict__ Whf,
        f16* __restrict__ gx) {
    __shared__ f16 sA[BM*BK], sB[BN*BK];

    // XCD-chunked swizzle: 6144 blocks, 8 XCDs -> 768 consecutive per XCD
    int wg   = blockIdx.x;
    int orig = (wg & 7) * 768 + (wg >> 3);
    int mblk = orig / 6, nblk = orig - mblk * 6;
    int m0 = mblk * BM, n0 = nblk * BN;

    int tid  = threadIdx.x;
    int lane = tid & 63, wid = tid >> 6;
    int wm = wid >> 1, wn = wid & 1;

    int acol = tid & 15, arow = tid >> 4;   // A staging: float4 granularity
    int bcol = tid & 7,  brow = tid >> 3;   // B staging: 16B (8 f16) granularity

    f32x4 acc[4][4] = {};

    for (int kb = 0; kb < 4; ++kb) {
        // ---- global loads into regs (issued before the barrier: overlap) ----
        f32x4 ra[8];
        u32x4 rb[4];
        #pragma unroll
        for (int p = 0; p < 8; ++p) {
            int row = p*16 + arow;
            ra[p] = *(const f32x4*)(X + (size_t)(m0+row)*I_DIM + kb*BK + acol*4);
        }
        #pragma unroll
        for (int p = 0; p < 4; ++p) {
            int row = p*32 + brow;
            rb[p] = *(const u32x4*)(Whf + (size_t)(n0+row)*I_DIM + kb*BK + bcol*8);
        }
        __syncthreads();   // prior iteration's LDS reads complete
        #pragma unroll
        for (int p = 0; p < 8; ++p) {
            int row = p*16 + arow;
            f16x4 hv;
            #pragma unroll
            for (int e = 0; e < 4; ++e) hv[e] = (f16)ra[p][e];
            *(f16x4*)((char*)sA + lds_swz(row, acol*8)) = hv;
        }
        #pragma unroll
        for (int p = 0; p < 4; ++p) {
            int row = p*32 + brow;
            *(u32x4*)((char*)sB + lds_swz(row, bcol*16)) = rb[p];
        }
        __syncthreads();
        // ---- MFMA over the two K=32 sub-steps ----
        #pragma unroll
        for (int kk = 0; kk < 2; ++kk) {
            f16x8 a[4], b[4];
            #pragma unroll
            for (int mi = 0; mi < 4; ++mi) {
                int row = wm*64 + mi*16 + (lane & 15);
                a[mi] = *(const f16x8*)((const char*)sA + lds_swz(row, kk*64 + (lane >> 4)*16));
            }
            #pragma unroll
            for (int ni = 0; ni < 4; ++ni) {
                int row = wn*64 + ni*16 + (lane & 15);
                b[ni] = *(const f16x8*)((const char*)sB + lds_swz(row, kk*64 + (lane >> 4)*16));
            }
            #pragma unroll
            for (int mi = 0; mi < 4; ++mi)
              #pragma unroll
              for (int ni = 0; ni < 4; ++ni)
                acc[mi][ni] = __builtin_amdgcn_mfma_f32_16x16x32_f16(a[mi], b[ni], acc[mi][ni], 0,0,0);
        }
    }
    // ---- epilogue: C/D layout col=lane&15, row=(lane>>4)*4+j ----
    #pragma unroll
    for (int mi = 0; mi < 4; ++mi) {
        int rbase = m0 + wm*64 + mi*16 + (lane >> 4)*4;
        #pragma unroll
        for (int ni = 0; ni < 4; ++ni) {
            int col = n0 + wn*64 + ni*16 + (lane & 15);
            #pragma unroll
            for (int j = 0; j < 4; ++j)
                gx[(size_t)(rbase + j)*N3 + col] = (f16)acc[mi][ni][j];
        }
    }
}

// ---------------------------------------------------------------------------
// Kernel 2: diagonal-GRU scan. 16384 chains (B*H), one lane each, 256 waves.
// gx (f16) pre-scaled by -log2e (r,z) / -2log2e (n): each gate is
// fma -> v_exp_f32 -> add -> v_rcp_f32. Batched 16-step double-buffer
// prefetch: 48 loads issued as a block, consumed one full batch later.
// ---------------------------------------------------------------------------
__global__ __launch_bounds__(64) void indgru_scan(
        const f16* __restrict__ gx, const float* __restrict__ bih,
        const float* __restrict__ bhh, const float* __restrict__ whh,
        float* __restrict__ out) {
    int lane = threadIdx.x;
    int b = blockIdx.x >> 2;
    int h = (blockIdx.x & 3) * 64 + lane;

    float whr = -L2E  * whh[h];
    float whz = -L2E  * whh[H_DIM + h];
    float whn = -2.0f*L2E * whh[2*H_DIM + h];
    float cr  = -L2E  * (bih[h] + bhh[h]);
    float cz  = -L2E  * (bih[H_DIM+h] + bhh[H_DIM+h]);
    float cn  = -2.0f*L2E * bih[2*H_DIM+h];
    float bhn = -2.0f*L2E * bhh[2*H_DIM+h];

    const size_t sg = (size_t)BATCH * N3;     // gx stride per t (elements)
    const size_t so = (size_t)BATCH * H_DIM;  // out stride per t
    const f16* pr = gx + (size_t)b*N3 + h;
    float* po = out + (size_t)b*H_DIM + h;

    f16 Ar[16], Az[16], An[16], Br[16], Bz[16], Bn[16];
    float hv = 0.f;

#define LOAD16(R, Z, N, tblk) do {                                  \
        const f16* _p = pr + (size_t)(tblk)*16*sg;                  \
        _Pragma("unroll")                                           \
        for (int _i = 0; _i < 16; ++_i) {                           \
            R[_i] = _p[0]; Z[_i] = _p[H_DIM]; N[_i] = _p[2*H_DIM];  \
            _p += sg;                                               \
        }                                                           \
    } while (0)

#define PROC16(R, Z, N) do {                                        \
        _Pragma("unroll")                                           \
        for (int _j = 0; _j < 16; ++_j) {                           \
            float ur = (float)R[_j] + cr;                           \
            float uz = (float)Z[_j] + cz;                           \
            float un = (float)N[_j] + cn;                           \
            float er = __builtin_amdgcn_exp2f(fmaf(whr, hv, ur));   \
            float r  = __builtin_amdgcn_rcpf(1.f + er);             \
            float ez = __builtin_amdgcn_exp2f(fmaf(whz, hv, uz));   \
            float z  = __builtin_amdgcn_rcpf(1.f + ez);             \
            float mn = fmaf(whn, hv, bhn);                          \
            float en = __builtin_amdgcn_exp2f(fmaf(r, mn, un));     \
            float q  = __builtin_amdgcn_rcpf(1.f + en);             \
            float hp1 = hv + 1.f;                                   \
            hv = fmaf(z, fmaf(-2.f, q, hp1), fmaf(2.f, q, -1.f));   \
            *po = hv; po += so;                                     \
        }                                                           \
    } while (0)

    LOAD16(Ar, Az, An, 0);
    for (int i = 0; i < 63; ++i) {
        LOAD16(Br, Bz, Bn, 2*i+1);
        PROC16(Ar, Az, An);
        LOAD16(Ar, Az, An, 2*i+2);
        PROC16(Br, Bz, Bn);
    }
    LOAD16(Br, Bz, Bn, 127);
    PROC16(Ar, Az, An);   // t-block 126
    PROC16(Br, Bz, Bn);   // t-block 127

    out[(size_t)T_LEN * so + (size_t)b*H_DIM + h] = hv;   // h_n
#undef LOAD16
#undef PROC16
}

// ---------------------------------------------------------------------------
extern "C" void kernel_launch(void* const* d_in, const int* in_sizes, int n_in,
                              void* d_out, int out_size, void* d_ws, size_t ws_size,
                              hipStream_t stream) {
    const float* x   = (const float*)d_in[0];
    const float* Wih = (const float*)d_in[1];
    const float* bih = (const float*)d_in[2];
    const float* bhh = (const float*)d_in[3];
    const float* whh = (const float*)d_in[4];
    float* out = (float*)d_out;

    char* ws = (char*)d_ws;
    f16* gxbuf = (f16*)ws;                                   // 192 MiB
    f16* Whf = (f16*)(ws + (size_t)M_ROWS*N3*sizeof(f16));   // 384 KiB

    convert_w<<<(N3*I_DIM)/256, 256, 0, stream>>>(Wih, Whf);
    gemm_gx<<<(M_ROWS/BM)*(N3/BN), 256, 0, stream>>>(x, Whf, gxbuf);
    indgru_scan<<<BATCH*(H_DIM/64), 64, 0, stream>>>(gxbuf, bih, bhh, whh, out);
}

// Round 3
// 518.004 us; speedup vs baseline: 1.1266x; 1.1266x over previous
//
#include <hip/hip_runtime.h>
#include <stdint.h>

#define T_LEN 2048
#define BATCH 64
#define I_DIM 256
#define H_DIM 256
#define N3    768
#define M_ROWS (T_LEN*BATCH)
#define L2E 1.4426950408889634f

typedef _Float16 f16;
typedef __attribute__((ext_vector_type(4))) float  f32x4;
typedef __attribute__((ext_vector_type(4))) _Float16 f16x4;
typedef __attribute__((ext_vector_type(8))) _Float16 f16x8;

// ---------------------------------------------------------------------------
// Kernel 0: W_ih [768][256] f32 -> f16, gate scale baked in (-L2E / -2L2E),
// PRE-SWIZZLED within each 64B (32-f16) chunk: logical 16B-unit lu placed at
// physical unit (lu + (row>>1)) & 3, so gemm can global_load_lds it linearly
// and ds_read it back conflict-free with the same rotation.
// ---------------------------------------------------------------------------
__global__ void convert_w(const float* __restrict__ W, f16* __restrict__ Whf) {
    int idx = blockIdx.x * 256 + threadIdx.x;      // 768*256
    int r = idx >> 8, c = idx & 255;
    float scale = (r < 2*H_DIM) ? -L2E : -2.0f*L2E;
    int chunk = c >> 5, lu = (c >> 3) & 3, e = c & 7;
    int pu = (lu + (r >> 1)) & 3;
    Whf[r*256 + chunk*32 + pu*8 + e] = (f16)(W[idx] * scale);
}

// ---------------------------------------------------------------------------
// Kernel 1: gx = X * W^T, f16 MFMA. BM=256 (4 t x 64 b), BN=128, BK=32,
// 512 threads (8 waves, 4m x 2n; per-wave 64x64). B double-buffered via
// global_load_lds (pre-swizzled source); A reg-staged f32->f16.
// Epilogue: LDS-shuffle C-tile into packed layout P[t/4][b][gh][4] f16 with
// 1KB-contiguous f16x8 stores per b.
// ---------------------------------------------------------------------------
#define BM 256
#define BN 128
#define BK 32

__global__ __launch_bounds__(512, 4) void gemm_gx(
        const float* __restrict__ X,
        const f16* __restrict__ Whf,
        f16* __restrict__ gxP) {
    __shared__ union {
        struct { f16 A[BM*BK]; f16 B[2][BN*BK]; } s;   // 16KB + 2*8KB
        f16 C[64*128*4];                               // 64KB epilogue staging
    } u;

    int wg   = blockIdx.x;                 // 3072 blocks
    int orig = (wg & 7) * 384 + (wg >> 3); // XCD-chunked swizzle (3072%8==0)
    int mblk = orig / 6, nblk = orig - mblk * 6;
    int m0 = mblk * BM, n0 = nblk * BN;

    int tid = threadIdx.x, lane = tid & 63, wid = tid >> 6;
    int wm = wid >> 1, wn = wid & 1;
    int arow = tid >> 3, acol = tid & 7;   // A staging: 8 thr/row, f32x4 each

    f32x4 acc[4][4] = {};

    // B tile loader: 8KB, 1KB per wave; LDS linear, source pre-swizzled.
    auto issueB = [&](int kb, int buf) {
        int lrow = wid * 16 + (lane >> 2);
        const f16* g = Whf + (size_t)(n0 + lrow) * 256 + kb * 32 + (lane & 3) * 8;
        f16* l = &u.s.B[buf][wid * 16 * BK];
        __builtin_amdgcn_global_load_lds(
            (const __attribute__((address_space(1))) void*)g,
            (__attribute__((address_space(3))) void*)l, 16, 0, 0);
    };

    issueB(0, 0);
    int cur = 0;
    for (int kb = 0; kb < 8; ++kb) {
        f32x4 ra[4];
        #pragma unroll
        for (int p = 0; p < 4; ++p)
            ra[p] = *(const f32x4*)(X + (size_t)(m0 + p*64 + arow) * I_DIM + kb*BK + acol*4);
        __syncthreads();   // prev MFMA LDS reads done; drains ra + B(kb)
        #pragma unroll
        for (int p = 0; p < 4; ++p) {
            int row = p*64 + arow;
            f16x4 hv;
            #pragma unroll
            for (int e = 0; e < 4; ++e) hv[e] = (f16)ra[p][e];
            int pu = ((acol >> 1) + (row >> 1)) & 3;
            *(f16x4*)((char*)u.s.A + row*64 + pu*16 + (acol & 1)*8) = hv;
        }
        __syncthreads();   // A writes visible
        if (kb < 7) issueB(kb + 1, cur ^ 1);   // flies under MFMA
        f16x8 af[4], bf[4];
        #pragma unroll
        for (int mi = 0; mi < 4; ++mi) {
            int lrow = wm*64 + mi*16 + (lane & 15);
            int pu = ((lane >> 4) + (lrow >> 1)) & 3;
            af[mi] = *(const f16x8*)((const char*)u.s.A + lrow*64 + pu*16);
        }
        #pragma unroll
        for (int ni = 0; ni < 4; ++ni) {
            int lrow = wn*64 + ni*16 + (lane & 15);
            int pu = ((lane >> 4) + (lrow >> 1)) & 3;
            bf[ni] = *(const f16x8*)((const char*)u.s.B[cur] + lrow*64 + pu*16);
        }
        #pragma unroll
        for (int mi = 0; mi < 4; ++mi)
          #pragma unroll
          for (int ni = 0; ni < 4; ++ni)
            acc[mi][ni] = __builtin_amdgcn_mfma_f32_16x16x32_f16(af[mi], bf[ni], acc[mi][ni], 0,0,0);
        cur ^= 1;
    }

    // ---- epilogue: frag -> ldsC[b][ghl][dt] -> packed global ----
    __syncthreads();   // last MFMA reads done before overwriting union
    #pragma unroll
    for (int mi = 0; mi < 4; ++mi) {
        // r = wm*64 + mi*16 + (lane>>4)*4 + j  ->  dt = wm, b = r & 63
        int bb0 = mi*16 + (lane >> 4)*4;
        #pragma unroll
        for (int ni = 0; ni < 4; ++ni) {
            int c = wn*64 + ni*16 + (lane & 15);
            #pragma unroll
            for (int j = 0; j < 4; ++j)
                u.C[(bb0 + j)*512 + c*4 + wm] = (f16)acc[mi][ni][j];
        }
    }
    __syncthreads();
    #pragma unroll
    for (int i = 0; i < 8; ++i) {
        int idx = i*512 + tid, bb = idx >> 6, w = idx & 63;
        f16x8 v = *(const f16x8*)&u.C[bb*512 + w*8];
        *(f16x8*)(gxP + ((size_t)(mblk*64 + bb)*N3 + n0)*4 + w*8) = v;
    }
}

// ---------------------------------------------------------------------------
// Kernel 2: diagonal-GRU scan over packed gx P[tb][b][gh][4] (f16).
// 16384 chains, one lane each. 12 x 8B loads per 16 steps, double-buffered.
// ---------------------------------------------------------------------------
__global__ __launch_bounds__(64) void indgru_scan(
        const f16* __restrict__ gxP, const float* __restrict__ bih,
        const float* __restrict__ bhh, const float* __restrict__ whh,
        float* __restrict__ out) {
    int lane = threadIdx.x;
    int b = blockIdx.x >> 2;
    int h = (blockIdx.x & 3) * 64 + lane;

    float whr = -L2E  * whh[h];
    float whz = -L2E  * whh[H_DIM + h];
    float whn = -2.0f*L2E * whh[2*H_DIM + h];
    float cr  = -L2E  * (bih[h] + bhh[h]);
    float cz  = -L2E  * (bih[H_DIM+h] + bhh[H_DIM+h]);
    float cn  = -2.0f*L2E * bih[2*H_DIM+h];
    float bhn = -2.0f*L2E * bhh[2*H_DIM+h];

    const size_t stb = (size_t)BATCH * N3 * 4;      // elems per tb step
    const size_t so  = (size_t)BATCH * H_DIM;
    const f16* pr = gxP + ((size_t)b * N3 + h) * 4; // +g*1024 per gate, +tb*stb
    float* po = out + (size_t)b * H_DIM + h;

    f16x4 Ar[4], Az[4], An[4], Br[4], Bz[4], Bn[4];
    float hv = 0.f;

#define LOADG(R, Z, N, grp) do {                                    \
        const f16* _p = pr + (size_t)(grp) * 4 * stb;               \
        _Pragma("unroll")                                           \
        for (int _q = 0; _q < 4; ++_q) {                            \
            R[_q] = *(const f16x4*)(_p);                            \
            Z[_q] = *(const f16x4*)(_p + H_DIM*4);                  \
            N[_q] = *(const f16x4*)(_p + 2*H_DIM*4);                \
            _p += stb;                                              \
        }                                                           \
    } while (0)

#define PROC16(R, Z, N) do {                                        \
        _Pragma("unroll")                                           \
        for (int _q = 0; _q < 4; ++_q)                              \
        _Pragma("unroll")                                           \
        for (int _j = 0; _j < 4; ++_j) {                            \
            float ur = (float)R[_q][_j] + cr;                       \
            float uz = (float)Z[_q][_j] + cz;                       \
            float un = (float)N[_q][_j] + cn;                       \
            float er = __builtin_amdgcn_exp2f(fmaf(whr, hv, ur));   \
            float r  = __builtin_amdgcn_rcpf(1.f + er);             \
            float ez = __builtin_amdgcn_exp2f(fmaf(whz, hv, uz));   \
            float z  = __builtin_amdgcn_rcpf(1.f + ez);             \
            float mn = fmaf(whn, hv, bhn);                          \
            float en = __builtin_amdgcn_exp2f(fmaf(r, mn, un));     \
            float q  = __builtin_amdgcn_rcpf(1.f + en);             \
            float hp1 = hv + 1.f;                                   \
            hv = fmaf(z, fmaf(-2.f, q, hp1), fmaf(2.f, q, -1.f));   \
            *po = hv; po += so;                                     \
        }                                                           \
    } while (0)

    LOADG(Ar, Az, An, 0);
    for (int i = 0; i < 63; ++i) {
        LOADG(Br, Bz, Bn, 2*i + 1);
        PROC16(Ar, Az, An);
        LOADG(Ar, Az, An, 2*i + 2);
        PROC16(Br, Bz, Bn);
    }
    LOADG(Br, Bz, Bn, 127);
    PROC16(Ar, Az, An);
    PROC16(Br, Bz, Bn);

    out[(size_t)T_LEN * so + (size_t)b * H_DIM + h] = hv;   // h_n
#undef LOADG
#undef PROC16
}

// ---------------------------------------------------------------------------
extern "C" void kernel_launch(void* const* d_in, const int* in_sizes, int n_in,
                              void* d_out, int out_size, void* d_ws, size_t ws_size,
                              hipStream_t stream) {
    const float* x   = (const float*)d_in[0];
    const float* Wih = (const float*)d_in[1];
    const float* bih = (const float*)d_in[2];
    const float* bhh = (const float*)d_in[3];
    const float* whh = (const float*)d_in[4];
    float* out = (float*)d_out;

    char* ws = (char*)d_ws;
    f16* gxP = (f16*)ws;                                     // 192 MiB packed
    f16* Whf = (f16*)(ws + (size_t)M_ROWS * N3 * sizeof(f16));

    convert_w<<<(N3*I_DIM)/256, 256, 0, stream>>>(Wih, Whf);
    gemm_gx<<<(M_ROWS/BM)*(N3/BN), 512, 0, stream>>>(x, Whf, gxP);
    indgru_scan<<<BATCH*(H_DIM/64), 64, 0, stream>>>(gxP, bih, bhh, whh, out);
}

// Round 4
// 499.946 us; speedup vs baseline: 1.1673x; 1.0361x over previous
//
#include <hip/hip_runtime.h>
#include <stdint.h>

#define T_LEN 2048
#define BATCH 64
#define I_DIM 256
#define H_DIM 256
#define N3    768
#define M_ROWS (T_LEN*BATCH)
#define L2E 1.4426950408889634f

typedef _Float16 f16;
typedef __attribute__((ext_vector_type(4))) float  f32x4;
typedef __attribute__((ext_vector_type(2))) _Float16 f16x2;
typedef __attribute__((ext_vector_type(8))) _Float16 f16x8;

// ---------------------------------------------------------------------------
// Kernel A: X [M,256] f32 -> f16, pre-XOR-swizzled in 16B units within each
// 8-unit (64-f16) group: out unit gu holds source unit (gu&~7)|((gu&7)^(m&7)).
// The GEMM global_load_lds's rows linearly and XOR-swizzles on ds_read.
// ---------------------------------------------------------------------------
__global__ __launch_bounds__(256) void convert_x(const float* __restrict__ X,
                                                 f16* __restrict__ Xs) {
    const int U = M_ROWS * 32;                 // 16B units
    for (int u = blockIdx.x * 256 + threadIdx.x; u < U; u += 2048 * 256) {
        int m = u >> 5, gu = u & 31;
        int su = (gu & 24) | ((gu & 7) ^ (m & 7));
        const float* src = X + (size_t)m * 256 + su * 8;
        f32x4 a = *(const f32x4*)src;
        f32x4 b = *(const f32x4*)(src + 4);
        f16x8 v;
        #pragma unroll
        for (int e = 0; e < 4; ++e) { v[e] = (f16)a[e]; v[4+e] = (f16)b[e]; }
        *(f16x8*)(Xs + (size_t)m * 256 + gu * 8) = v;
    }
}

// ---------------------------------------------------------------------------
// Kernel B: W_ih [768,256] f32 -> f16, gate scale baked in (-L2E r,z; -2L2E n),
// same pre-XOR-swizzle.
// ---------------------------------------------------------------------------
__global__ __launch_bounds__(256) void convert_w(const float* __restrict__ W,
                                                 f16* __restrict__ Ws) {
    int u = blockIdx.x * 256 + threadIdx.x;    // 24576 units
    int n = u >> 5, gu = u & 31;
    float scale = (n < 512) ? -L2E : -2.0f * L2E;
    int su = (gu & 24) | ((gu & 7) ^ (n & 7));
    const float* src = W + (size_t)n * 256 + su * 8;
    f32x4 a = *(const f32x4*)src;
    f32x4 b = *(const f32x4*)(src + 4);
    f16x8 v;
    #pragma unroll
    for (int e = 0; e < 4; ++e) { v[e] = (f16)(a[e]*scale); v[4+e] = (f16)(b[e]*scale); }
    *(f16x8*)(Ws + (size_t)n * 256 + gu * 8) = v;
}

// ---------------------------------------------------------------------------
// Kernel C: gx = Xs * Ws^T, f16 MFMA, m97 structure. BM=BN=128, BK=64,
// 256 thr (2x2 waves, 64x64 each), glds-direct both operands, 32KiB LDS,
// XOR-swizzled ds_read_b128. Epilogue: LDS shuffle -> packed P2 layout
// [t/2][b][gh][2] f16 with 512B-contiguous runs per b.
// ---------------------------------------------------------------------------
__global__ __launch_bounds__(256, 4) void gemm_gx(
        const f16* __restrict__ Xs,
        const f16* __restrict__ Ws,
        f16* __restrict__ gxP) {
    __shared__ union {
        struct { f16 A[128*64]; f16 B[128*64]; } s;   // 16KB + 16KB
        f16 C[64*128*2];                               // 32KB epilogue
    } u;

    int wg   = blockIdx.x;                  // 6144 blocks
    int orig = (wg & 7) * 768 + (wg >> 3);  // XCD-chunked (6144%8==0)
    int mblk = orig / 6, nblk = orig - mblk * 6;
    int m0 = mblk * 128, n0 = nblk * 128;

    int tid = threadIdx.x, lane = tid & 63, wid = tid >> 6;
    int wm = wid >> 1, wn = wid & 1;

    f32x4 acc[4][4] = {};

    for (int kb = 0; kb < 4; ++kb) {
        if (kb) __syncthreads();            // prev frag reads done
        // glds: A tile 16KB (4 rounds) + B tile 16KB (4 rounds), linear LDS
        #pragma unroll
        for (int rd = 0; rd < 4; ++rd) {
            int uu = rd * 256 + tid;        // 16B unit in tile
            int row = uu >> 3, pl = uu & 7;
            const f16* ga = Xs + (size_t)(m0 + row) * 256 + kb * 64 + pl * 8;
            __builtin_amdgcn_global_load_lds(
                (const __attribute__((address_space(1))) void*)ga,
                (__attribute__((address_space(3))) void*)(u.s.A + uu * 8), 16, 0, 0);
        }
        #pragma unroll
        for (int rd = 0; rd < 4; ++rd) {
            int uu = rd * 256 + tid;
            int row = uu >> 3, pl = uu & 7;
            const f16* gb = Ws + (size_t)(n0 + row) * 256 + kb * 64 + pl * 8;
            __builtin_amdgcn_global_load_lds(
                (const __attribute__((address_space(1))) void*)gb,
                (__attribute__((address_space(3))) void*)(u.s.B + uu * 8), 16, 0, 0);
        }
        __syncthreads();                    // vmcnt(0) drain before barrier
        #pragma unroll
        for (int kk = 0; kk < 2; ++kk) {
            int c16 = kk * 4 + (lane >> 4);
            f16x8 af[4], bf[4];
            #pragma unroll
            for (int mi = 0; mi < 4; ++mi) {
                int row = wm*64 + mi*16 + (lane & 15);
                af[mi] = *(const f16x8*)((const char*)u.s.A + row*128 + ((c16 ^ (row & 7)) * 16));
            }
            #pragma unroll
            for (int ni = 0; ni < 4; ++ni) {
                int row = wn*64 + ni*16 + (lane & 15);
                bf[ni] = *(const f16x8*)((const char*)u.s.B + row*128 + ((c16 ^ (row & 7)) * 16));
            }
            #pragma unroll
            for (int mi = 0; mi < 4; ++mi)
              #pragma unroll
              for (int ni = 0; ni < 4; ++ni)
                acc[mi][ni] = __builtin_amdgcn_mfma_f32_16x16x32_f16(af[mi], bf[ni], acc[mi][ni], 0,0,0);
        }
    }

    // ---- epilogue: frags -> Cl[b][ghl][tl] -> packed global ----
    __syncthreads();                        // last frag reads done
    #pragma unroll
    for (int mi = 0; mi < 4; ++mi) {
        int rr = mi*16 + (lane >> 4)*4;     // r = wm*64 + rr + j; b=rr+j, tl=wm
        #pragma unroll
        for (int ni = 0; ni < 4; ++ni) {
            int c = wn*64 + ni*16 + (lane & 15);
            #pragma unroll
            for (int j = 0; j < 4; ++j)
                u.C[(rr + j)*256 + c*2 + wm] = (f16)acc[mi][ni][j];
        }
    }
    __syncthreads();
    #pragma unroll
    for (int i = 0; i < 8; ++i) {
        int uu = i*256 + tid, b = uu >> 5, q = uu & 31;   // 512B per b
        f16x8 v = *(const f16x8*)(u.C + b*256 + q*8);
        *(f16x8*)(gxP + (size_t)(mblk*64 + b)*1536 + n0*2 + q*8) = v;
    }
}

// ---------------------------------------------------------------------------
// Kernel D: diagonal-GRU scan over packed P2[t/2][b][gh][2] (f16).
// 16384 chains, one lane each (256 waves, 1/CU). 24 x 4B loads per 16 steps,
// double-buffered one full batch ahead.
// ---------------------------------------------------------------------------
__global__ __launch_bounds__(64) void indgru_scan(
        const f16* __restrict__ gxP, const float* __restrict__ bih,
        const float* __restrict__ bhh, const float* __restrict__ whh,
        float* __restrict__ out) {
    int lane = threadIdx.x;
    int b = blockIdx.x >> 2;
    int h = (blockIdx.x & 3) * 64 + lane;

    float whr = -L2E  * whh[h];
    float whz = -L2E  * whh[H_DIM + h];
    float whn = -2.0f*L2E * whh[2*H_DIM + h];
    float cr  = -L2E  * (bih[h] + bhh[h]);
    float cz  = -L2E  * (bih[H_DIM+h] + bhh[H_DIM+h]);
    float cn  = -2.0f*L2E * bih[2*H_DIM+h];
    float bhn = -2.0f*L2E * bhh[2*H_DIM+h];

    const size_t stp = (size_t)BATCH * N3 * 2;   // f16 per t-pair (98304)
    const size_t so  = (size_t)BATCH * H_DIM;
    const f16* pr = gxP + (size_t)b * 1536 + h * 2;
    float* po = out + (size_t)b * H_DIM + h;

    f16x2 Ar[8], Az[8], An[8], Br[8], Bz[8], Bn[8];
    float hv = 0.f;

#define LOADG(R, Z, N, grp) do {                                    \
        const f16* _p = pr + (size_t)(grp) * 8 * stp;               \
        _Pragma("unroll")                                           \
        for (int _q = 0; _q < 8; ++_q) {                            \
            R[_q] = *(const f16x2*)(_p);                            \
            Z[_q] = *(const f16x2*)(_p + 512);                      \
            N[_q] = *(const f16x2*)(_p + 1024);                     \
            _p += stp;                                              \
        }                                                           \
    } while (0)

#define PROC16(R, Z, N) do {                                        \
        _Pragma("unroll")                                           \
        for (int _q = 0; _q < 8; ++_q)                              \
        _Pragma("unroll")                                           \
        for (int _j = 0; _j < 2; ++_j) {                            \
            float ur = (float)R[_q][_j] + cr;                       \
            float uz = (float)Z[_q][_j] + cz;                       \
            float un = (float)N[_q][_j] + cn;                       \
            float er = __builtin_amdgcn_exp2f(fmaf(whr, hv, ur));   \
            float r  = __builtin_amdgcn_rcpf(1.f + er);             \
            float ez = __builtin_amdgcn_exp2f(fmaf(whz, hv, uz));   \
            float z  = __builtin_amdgcn_rcpf(1.f + ez);             \
            float mn = fmaf(whn, hv, bhn);                          \
            float en = __builtin_amdgcn_exp2f(fmaf(r, mn, un));     \
            float q  = __builtin_amdgcn_rcpf(1.f + en);             \
            float hp1 = hv + 1.f;                                   \
            hv = fmaf(z, fmaf(-2.f, q, hp1), fmaf(2.f, q, -1.f));   \
            *po = hv; po += so;                                     \
        }                                                           \
    } while (0)

    LOADG(Ar, Az, An, 0);
    for (int i = 0; i < 63; ++i) {
        LOADG(Br, Bz, Bn, 2*i + 1);
        PROC16(Ar, Az, An);
        LOADG(Ar, Az, An, 2*i + 2);
        PROC16(Br, Bz, Bn);
    }
    LOADG(Br, Bz, Bn, 127);
    PROC16(Ar, Az, An);
    PROC16(Br, Bz, Bn);

    out[(size_t)T_LEN * so + (size_t)b * H_DIM + h] = hv;   // h_n
#undef LOADG
#undef PROC16
}

// ---------------------------------------------------------------------------
extern "C" void kernel_launch(void* const* d_in, const int* in_sizes, int n_in,
                              void* d_out, int out_size, void* d_ws, size_t ws_size,
                              hipStream_t stream) {
    const float* x   = (const float*)d_in[0];
    const float* Wih = (const float*)d_in[1];
    const float* bih = (const float*)d_in[2];
    const float* bhh = (const float*)d_in[3];
    const float* whh = (const float*)d_in[4];
    float* out = (float*)d_out;

    char* ws = (char*)d_ws;
    f16* gxP = (f16*)ws;                                       // 192 MiB packed
    f16* Xs  = (f16*)(ws + (size_t)M_ROWS*N3*sizeof(f16));     // 64 MiB
    f16* Wsc = Xs + (size_t)M_ROWS*I_DIM;                      // 384 KiB

    convert_x<<<2048, 256, 0, stream>>>(x, Xs);
    convert_w<<<(N3*I_DIM/8)/256, 256, 0, stream>>>(Wih, Wsc);
    gemm_gx<<<(M_ROWS/128)*(N3/128), 256, 0, stream>>>(Xs, Wsc, gxP);
    indgru_scan<<<BATCH*(H_DIM/64), 64, 0, stream>>>(gxP, bih, bhh, whh, out);
}

// Round 6
// 478.434 us; speedup vs baseline: 1.2198x; 1.0450x over previous
//
#include <hip/hip_runtime.h>
#include <stdint.h>

#define T_LEN 2048
#define BATCH 64
#define I_DIM 256
#define H_DIM 256
#define N3    768
#define M_ROWS (T_LEN*BATCH)
#define L2E 1.4426950408889634f

typedef _Float16 f16;
typedef __attribute__((ext_vector_type(4))) float  f32x4;
typedef __attribute__((ext_vector_type(2))) _Float16 f16x2;
typedef __attribute__((ext_vector_type(8))) _Float16 f16x8;

// ---------------------------------------------------------------------------
// Kernel A: X [M,256] f32 -> f16, pre-XOR-swizzled in 16B units within each
// 8-unit (64-f16) group: out unit gu holds source unit (gu&~7)|((gu&7)^(m&7)).
// The GEMM global_load_lds's rows linearly and XOR-swizzles on ds_read.
// ---------------------------------------------------------------------------
__global__ __launch_bounds__(256) void convert_x(const float* __restrict__ X,
                                                 f16* __restrict__ Xs) {
    const int U = M_ROWS * 32;                 // 16B units
    for (int u = blockIdx.x * 256 + threadIdx.x; u < U; u += 2048 * 256) {
        int m = u >> 5, gu = u & 31;
        int su = (gu & 24) | ((gu & 7) ^ (m & 7));
        const float* src = X + (size_t)m * 256 + su * 8;
        f32x4 a = *(const f32x4*)src;
        f32x4 b = *(const f32x4*)(src + 4);
        f16x8 v;
        #pragma unroll
        for (int e = 0; e < 4; ++e) { v[e] = (f16)a[e]; v[4+e] = (f16)b[e]; }
        *(f16x8*)(Xs + (size_t)m * 256 + gu * 8) = v;
    }
}

// ---------------------------------------------------------------------------
// Kernel B: W_ih [768,256] f32 -> f16, gate scale baked in (-L2E r,z; -2L2E n),
// same pre-XOR-swizzle.
// ---------------------------------------------------------------------------
__global__ __launch_bounds__(256) void convert_w(const float* __restrict__ W,
                                                 f16* __restrict__ Ws) {
    int u = blockIdx.x * 256 + threadIdx.x;    // 24576 units
    int n = u >> 5, gu = u & 31;
    float scale = (n < 512) ? -L2E : -2.0f * L2E;
    int su = (gu & 24) | ((gu & 7) ^ (n & 7));
    const float* src = W + (size_t)n * 256 + su * 8;
    f32x4 a = *(const f32x4*)src;
    f32x4 b = *(const f32x4*)(src + 4);
    f16x8 v;
    #pragma unroll
    for (int e = 0; e < 4; ++e) { v[e] = (f16)(a[e]*scale); v[4+e] = (f16)(b[e]*scale); }
    *(f16x8*)(Ws + (size_t)n * 256 + gu * 8) = v;
}

// ---------------------------------------------------------------------------
// Kernel C: gx = Xs * Ws^T, f16 MFMA, m97 structure. BM=BN=128, BK=64,
// 256 thr (2x2 waves, 64x64 each), glds-direct both operands, 32KiB LDS,
// XOR-swizzled ds_read_b128. Epilogue: LDS shuffle -> packed P2 layout
// [t/2][b][gh][2] f16 with 512B-contiguous runs per b.
// ---------------------------------------------------------------------------
__global__ __launch_bounds__(256, 4) void gemm_gx(
        const f16* __restrict__ Xs,
        const f16* __restrict__ Ws,
        f16* __restrict__ gxP) {
    __shared__ union {
        struct { f16 A[128*64]; f16 B[128*64]; } s;   // 16KB + 16KB
        f16 C[64*128*2];                               // 32KB epilogue
    } u;

    int wg   = blockIdx.x;                  // 6144 blocks
    int orig = (wg & 7) * 768 + (wg >> 3);  // XCD-chunked (6144%8==0)
    int mblk = orig / 6, nblk = orig - mblk * 6;
    int m0 = mblk * 128, n0 = nblk * 128;

    int tid = threadIdx.x, lane = tid & 63, wid = tid >> 6;
    int wm = wid >> 1, wn = wid & 1;

    f32x4 acc[4][4] = {};

    for (int kb = 0; kb < 4; ++kb) {
        if (kb) __syncthreads();            // prev frag reads done
        // glds: A tile 16KB (4 rounds) + B tile 16KB (4 rounds), linear LDS
        #pragma unroll
        for (int rd = 0; rd < 4; ++rd) {
            int uu = rd * 256 + tid;        // 16B unit in tile
            int row = uu >> 3, pl = uu & 7;
            const f16* ga = Xs + (size_t)(m0 + row) * 256 + kb * 64 + pl * 8;
            __builtin_amdgcn_global_load_lds(
                (const __attribute__((address_space(1))) void*)ga,
                (__attribute__((address_space(3))) void*)(u.s.A + uu * 8), 16, 0, 0);
        }
        #pragma unroll
        for (int rd = 0; rd < 4; ++rd) {
            int uu = rd * 256 + tid;
            int row = uu >> 3, pl = uu & 7;
            const f16* gb = Ws + (size_t)(n0 + row) * 256 + kb * 64 + pl * 8;
            __builtin_amdgcn_global_load_lds(
                (const __attribute__((address_space(1))) void*)gb,
                (__attribute__((address_space(3))) void*)(u.s.B + uu * 8), 16, 0, 0);
        }
        __syncthreads();                    // vmcnt(0) drain before barrier
        #pragma unroll
        for (int kk = 0; kk < 2; ++kk) {
            int c16 = kk * 4 + (lane >> 4);
            f16x8 af[4], bf[4];
            #pragma unroll
            for (int mi = 0; mi < 4; ++mi) {
                int row = wm*64 + mi*16 + (lane & 15);
                af[mi] = *(const f16x8*)((const char*)u.s.A + row*128 + ((c16 ^ (row & 7)) * 16));
            }
            #pragma unroll
            for (int ni = 0; ni < 4; ++ni) {
                int row = wn*64 + ni*16 + (lane & 15);
                bf[ni] = *(const f16x8*)((const char*)u.s.B + row*128 + ((c16 ^ (row & 7)) * 16));
            }
            #pragma unroll
            for (int mi = 0; mi < 4; ++mi)
              #pragma unroll
              for (int ni = 0; ni < 4; ++ni)
                acc[mi][ni] = __builtin_amdgcn_mfma_f32_16x16x32_f16(af[mi], bf[ni], acc[mi][ni], 0,0,0);
        }
    }

    // ---- epilogue: frags -> Cl[b][ghl][tl] -> packed global ----
    __syncthreads();                        // last frag reads done
    #pragma unroll
    for (int mi = 0; mi < 4; ++mi) {
        int rr = mi*16 + (lane >> 4)*4;     // r = wm*64 + rr + j; b=rr+j, tl=wm
        #pragma unroll
        for (int ni = 0; ni < 4; ++ni) {
            int c = wn*64 + ni*16 + (lane & 15);
            #pragma unroll
            for (int j = 0; j < 4; ++j)
                u.C[(rr + j)*256 + c*2 + wm] = (f16)acc[mi][ni][j];
        }
    }
    __syncthreads();
    #pragma unroll
    for (int i = 0; i < 8; ++i) {
        int uu = i*256 + tid, b = uu >> 5, q = uu & 31;   // 512B per b
        f16x8 v = *(const f16x8*)(u.C + b*256 + q*8);
        *(f16x8*)(gxP + (size_t)(mblk*64 + b)*1536 + n0*2 + q*8) = v;
    }
}

// ---------------------------------------------------------------------------
// Kernel D: diagonal-GRU scan over packed P2[t/2][b][gh][2] (f16).
// 16384 chains, one lane each (256 waves, 1/CU). 24 x 4B loads per 16 steps,
// double-buffered one full batch ahead. launch_bounds(64,1): occupancy is
// structurally 1 wave/SIMD, so give the compiler the whole VGPR file —
// round-4's 48-VGPR allocation sank the prefetch loads to their uses and
// exposed full memory latency (193 cyc/step, VALUBusy 16%). sched_barrier(0)
// fences pin the load batches ahead of the compute batches.
// ---------------------------------------------------------------------------
__global__ __launch_bounds__(64, 1) void indgru_scan(
        const f16* __restrict__ gxP, const float* __restrict__ bih,
        const float* __restrict__ bhh, const float* __restrict__ whh,
        float* __restrict__ out) {
    int lane = threadIdx.x;
    int b = blockIdx.x >> 2;
    int h = (blockIdx.x & 3) * 64 + lane;

    float whr = -L2E  * whh[h];
    float whz = -L2E  * whh[H_DIM + h];
    float whn = -2.0f*L2E * whh[2*H_DIM + h];
    float cr  = -L2E  * (bih[h] + bhh[h]);
    float cz  = -L2E  * (bih[H_DIM+h] + bhh[H_DIM+h]);
    float cn  = -2.0f*L2E * bih[2*H_DIM+h];
    float bhn = -2.0f*L2E * bhh[2*H_DIM+h];

    const size_t stp = (size_t)BATCH * N3 * 2;   // f16 per t-pair (98304)
    const size_t so  = (size_t)BATCH * H_DIM;
    const f16* pr = gxP + (size_t)b * 1536 + h * 2;
    float* po = out + (size_t)b * H_DIM + h;

    f16x2 Ar[8], Az[8], An[8], Br[8], Bz[8], Bn[8];
    float hv = 0.f;

#define LOADG(R, Z, N, grp) do {                                    \
        const f16* _p = pr + (size_t)(grp) * 8 * stp;               \
        _Pragma("unroll")                                           \
        for (int _q = 0; _q < 8; ++_q) {                            \
            R[_q] = *(const f16x2*)(_p);                            \
            Z[_q] = *(const f16x2*)(_p + 512);                      \
            N[_q] = *(const f16x2*)(_p + 1024);                     \
            _p += stp;                                              \
        }                                                           \
    } while (0)

#define PROC16(R, Z, N) do {                                        \
        _Pragma("unroll")                                           \
        for (int _q = 0; _q < 8; ++_q)                              \
        _Pragma("unroll")                                           \
        for (int _j = 0; _j < 2; ++_j) {                            \
            float ur = (float)R[_q][_j] + cr;                       \
            float uz = (float)Z[_q][_j] + cz;                       \
            float un = (float)N[_q][_j] + cn;                       \
            float er = __builtin_amdgcn_exp2f(fmaf(whr, hv, ur));   \
            float r  = __builtin_amdgcn_rcpf(1.f + er);             \
            float ez = __builtin_amdgcn_exp2f(fmaf(whz, hv, uz));   \
            float z  = __builtin_amdgcn_rcpf(1.f + ez);             \
            float mn = fmaf(whn, hv, bhn);                          \
            float en = __builtin_amdgcn_exp2f(fmaf(r, mn, un));     \
            float q  = __builtin_amdgcn_rcpf(1.f + en);             \
            float hp1 = hv + 1.f;                                   \
            hv = fmaf(z, fmaf(-2.f, q, hp1), fmaf(2.f, q, -1.f));   \
            *po = hv; po += so;                                     \
        }                                                           \
    } while (0)

#define FENCE __builtin_amdgcn_sched_barrier(0)

    LOADG(Ar, Az, An, 0);
    FENCE;
    for (int i = 0; i < 63; ++i) {
        LOADG(Br, Bz, Bn, 2*i + 1);   // issue batch k+1 ...
        FENCE;
        PROC16(Ar, Az, An);           // ... then crunch batch k (~1500 cyc)
        FENCE;
        LOADG(Ar, Az, An, 2*i + 2);
        FENCE;
        PROC16(Br, Bz, Bn);
        FENCE;
    }
    LOADG(Br, Bz, Bn, 127);
    FENCE;
    PROC16(Ar, Az, An);
    PROC16(Br, Bz, Bn);

    out[(size_t)T_LEN * so + (size_t)b * H_DIM + h] = hv;   // h_n
#undef LOADG
#undef PROC16
#undef FENCE
}

// ---------------------------------------------------------------------------
extern "C" void kernel_launch(void* const* d_in, const int* in_sizes, int n_in,
                              void* d_out, int out_size, void* d_ws, size_t ws_size,
                              hipStream_t stream) {
    const float* x   = (const float*)d_in[0];
    const float* Wih = (const float*)d_in[1];
    const float* bih = (const float*)d_in[2];
    const float* bhh = (const float*)d_in[3];
    const float* whh = (const float*)d_in[4];
    float* out = (float*)d_out;

    char* ws = (char*)d_ws;
    f16* gxP = (f16*)ws;                                       // 192 MiB packed
    f16* Xs  = (f16*)(ws + (size_t)M_ROWS*N3*sizeof(f16));     // 64 MiB
    f16* Wsc = Xs + (size_t)M_ROWS*I_DIM;                      // 384 KiB

    convert_x<<<2048, 256, 0, stream>>>(x, Xs);
    convert_w<<<(N3*I_DIM/8)/256, 256, 0, stream>>>(Wih, Wsc);
    gemm_gx<<<(M_ROWS/128)*(N3/128), 256, 0, stream>>>(Xs, Wsc, gxP);
    indgru_scan<<<BATCH*(H_DIM/64), 64, 0, stream>>>(gxP, bih, bhh, whh, out);
}